// Round 3
// baseline (186.274 us; speedup 1.0000x reference)
//
#include <hip/hip_runtime.h>
#include <stdint.h>

#define DM 1024
#define NH 16
#define HD 64
#define BB 2
#define TT 2048
#define MT (BB*TT)   // 4096 rows total

typedef __bf16 bfrag __attribute__((ext_vector_type(8)));     // 8 bf16 = 4 VGPR (MFMA A/B)
typedef float  f32x4 __attribute__((ext_vector_type(4)));     // MFMA C/D

__device__ __forceinline__ unsigned short f2bf(float f) {
  union { float f; unsigned u; } v; v.f = f;
  unsigned r = v.u + 0x7fffu + ((v.u >> 16) & 1u);  // RNE
  return (unsigned short)(r >> 16);
}

__device__ __forceinline__ unsigned short f2bf_hw(float f) {
  __bf16 b = (__bf16)f;                 // hardware cvt
  union { __bf16 b; unsigned short u; } v; v.b = b;
  return v.u;
}

__device__ __forceinline__ unsigned int pack2bf(float a, float b) {
  union { __bf16 h[2]; unsigned int u; } v;
  v.h[0] = (__bf16)a; v.h[1] = (__bf16)b;   // fuses to v_cvt_pk_bf16_f32
  return v.u;
}

__device__ __forceinline__ void async16(const void* g, void* l) {
  __builtin_amdgcn_global_load_lds(
      (const __attribute__((address_space(1))) unsigned int*)g,
      (__attribute__((address_space(3))) unsigned int*)l, 16, 0, 0);
}

// compiler-fenced raw barrier: keeps hipcc from migrating LDS/VMEM ops across
// the hardware barrier while NOT draining vmcnt (unlike __syncthreads()).
#define CBAR() do { asm volatile("" ::: "memory"); \
                    __builtin_amdgcn_s_barrier();  \
                    asm volatile("" ::: "memory"); } while (0)

// ---------------------------------------------------------------- cvt fp32->bf16
__global__ __launch_bounds__(256) void cvt_kernel(
    const float* __restrict__ x,  const float* __restrict__ Wq,
    const float* __restrict__ Wk, const float* __restrict__ Wv,
    const float* __restrict__ Wo,
    unsigned short* __restrict__ xb, unsigned short* __restrict__ wqkv,
    unsigned short* __restrict__ wob) {
  int i = blockIdx.x * 256 + threadIdx.x;       // one float4 group each
  const int NX = MT * DM / 4;                   // 1048576 groups of x
  const int NW = DM * DM / 4;                   // 262144 per weight
  const float* src; unsigned short* dst; int off;
  if      (i < NX)        { src = x;  dst = xb;              off = i; }
  else if (i < NX + NW)   { src = Wq; dst = wqkv;            off = i - NX; }
  else if (i < NX + 2*NW) { src = Wk; dst = wqkv + DM*DM;    off = i - NX - NW; }
  else if (i < NX + 3*NW) { src = Wv; dst = wqkv + 2*DM*DM;  off = i - NX - 2*NW; }
  else                    { src = Wo; dst = wob;             off = i - NX - 3*NW; }
  float4 v = ((const float4*)src)[off];
  ushort4 o;
  o.x = f2bf(v.x); o.y = f2bf(v.y); o.z = f2bf(v.z); o.w = f2bf(v.w);
  ((ushort4*)dst)[off] = o;
}

// ---------------------------------------------------------------- QKV GEMM
// 256x192 tile, BK=64, 8 waves (2M x 4N), 4 phases per K-tile, counted vmcnt.
// Grid = 16x16 = 256 blocks = EXACTLY 1 block/CU, 100% fill (round-1's 256x256
// left 64 CUs idle; round-2's 4-wave/2-block variant refuted cross-block
// overlap). LDS 112 KB.
//
// LDS ring: 8 slots = {A,B} x {K-lo,K-hi} x {2 bufs}. Part h = 4*t + pi,
// pi: 0=A-lo 1=B-lo 2=A-hi 3=B-hi. A part = 256x32 = 16KB = 2 calls/wave.
// B part = 192x32 = 12KB = 12 1KB-chunks: wave w stages chunk w, waves 0-3
// also chunk 8+w (2 calls for waves 0-3, 1 for waves 4-7).
// Phase P (=4t+p) stages part h=P+6. Reads: ph0 {A-lo(M0-3), B-lo},
// ph1 {A-lo(M4-7), bf reused}, ph2 {A-hi(M0-3), B-hi}, ph3 {A-hi(M4-7)}.
// Per-wave outstanding-load accounting (g0 = waves 0-3: 8 loads/tile,
// g1 = waves 4-7: 6 loads/tile): exact allowed residuals are 8/6 steady,
// 4/3 at t=14/ph3, 0 at t=15/ph1. We use the STRICTER g1 constants
// uniformly (6 / 3 / 0) -- correct for both groups, no wave branches.
// Slot-reuse safety: part (t,pi)'s last LDS read is >=1 barrier before
// (t+2,pi)'s staging issue (A-lo: read ph1, re-staged ph2; B-lo: ph0/ph3;
// A-hi: ph3, re-staged ph0(t+1); B-hi: ph2, re-staged ph1(t+1)).
// Swizzle: 32-elem rows, 16B chunk c ^= (row>>1)&3, folded into global addr.
__global__ __launch_bounds__(512, 2) void gemm_qkv(
    const unsigned short* __restrict__ A, const unsigned short* __restrict__ Bm,
    const float* __restrict__ bias0, const float* __restrict__ bias1,
    const float* __restrict__ bias2,
    unsigned short* __restrict__ Qo, unsigned short* __restrict__ Ko,
    unsigned short* __restrict__ Vo) {
  const int tid = threadIdx.x;
  const int wave = tid >> 6, lane = tid & 63;
  const int lr = lane & 15, quad = lane >> 4;
  // XCD swizzle: 256 WGs = 8 XCDs x 32; n-panel-major within an XCD chunk
  // (each XCD keeps 2 B-panels = 768 KB L2-resident, streams A).
  const int flat = blockIdx.x;
  const int s = (flat & 7) * 32 + (flat >> 3);
  const int m0 = (s & 15) * 256, n0 = (s >> 4) * 192;

  __shared__ __align__(16) unsigned short sA[2][2][256 * 32];  // 64 KB
  __shared__ __align__(16) unsigned short sB[2][2][192 * 32];  // 48 KB

  const f32x4 zero = {0.f, 0.f, 0.f, 0.f};
  f32x4 acc[8][3];
#pragma unroll
  for (int i = 0; i < 8; i++)
#pragma unroll
    for (int j = 0; j < 3; j++) acc[i][j] = zero;

  const int wm = (wave >> 2) * 128, wn = (wave & 3) * 48;

  auto stagePart = [&](int h) {
    if (h >= 64) return;                  // 16 tiles x 4 parts
    const int ts = h >> 2, pi = h & 3;
    const int buf = ts & 1, hk = pi >> 1; // hk: 0=lo,1=hi
    const int k0 = ts * 64 + (hk << 5);
    if (pi & 1) {                         // B part: 192 rows x 32 = 12 chunks
      unsigned short* dst = &sB[buf][hk][0];
      {
        int fb = wave * 512;
        int fl = fb + lane * 8;
        int row = fl >> 5, c = (fl >> 3) & 3;
        async16(Bm + (size_t)(n0 + row) * 1024 + k0 + ((c ^ ((row >> 1) & 3)) << 3),
                dst + fb);
      }
      if (wave < 4) {
        int fb = 4096 + wave * 512;
        int fl = fb + lane * 8;
        int row = fl >> 5, c = (fl >> 3) & 3;
        async16(Bm + (size_t)(n0 + row) * 1024 + k0 + ((c ^ ((row >> 1) & 3)) << 3),
                dst + fb);
      }
    } else {                              // A part: 256 rows x 32, 2 calls/wave
      unsigned short* dst = &sA[buf][hk][0];
#pragma unroll
      for (int rep = 0; rep < 2; ++rep) {
        int fb = rep * 4096 + wave * 512;
        int fl = fb + lane * 8;
        int row = fl >> 5, c = (fl >> 3) & 3;
        async16(A + (size_t)(m0 + row) * 1024 + k0 + ((c ^ ((row >> 1) & 3)) << 3),
                dst + fb);
      }
    }
  };

  // prologue: parts 0..5 = tile0 complete + tile1 lo; wait tile0-lo landed
#pragma unroll
  for (int h = 0; h < 6; ++h) stagePart(h);
  asm volatile("s_waitcnt vmcnt(6)" ::: "memory");
  CBAR();

  bfrag af[4], bf[3];
#pragma unroll 1
  for (int t = 0; t < 16; ++t) {
    const int buf = t & 1;
    const int P0 = 4 * t;

    auto rdA = [&](int hk, int ihalf) {
#pragma unroll
      for (int i = 0; i < 4; i++) {
        int ra = wm + ihalf * 64 + i * 16 + lr;
        af[i] = *(const bfrag*)&sA[buf][hk][ra * 32 + ((quad ^ ((ra >> 1) & 3)) << 3)];
      }
    };
    auto rdB = [&](int hk) {
#pragma unroll
      for (int jj = 0; jj < 3; jj++) {
        int rb = wn + jj * 16 + lr;
        bf[jj] = *(const bfrag*)&sB[buf][hk][rb * 32 + ((quad ^ ((rb >> 1) & 3)) << 3)];
      }
    };
    auto domfma = [&](int ib) {
      __builtin_amdgcn_s_setprio(1);
#pragma unroll
      for (int i = 0; i < 4; i++)
#pragma unroll
        for (int jj = 0; jj < 3; jj++)
          acc[ib + i][jj] = __builtin_amdgcn_mfma_f32_16x16x32_bf16(
              af[i], bf[jj], acc[ib + i][jj], 0, 0, 0);
      __builtin_amdgcn_s_setprio(0);
    };

    // ---- phase 0: kk0, M-frags 0-3 (reads A-lo,B-lo; stages (t+1,A-hi))
    rdA(0, 0); rdB(0);
    stagePart(P0 + 6);
    CBAR();
    domfma(0);
    CBAR();
    // ---- phase 1: kk0, M-frags 4-7 (bf reused; stages (t+1,B-hi))
    rdA(0, 1);
    stagePart(P0 + 7);
    if (t == 15) { asm volatile("s_waitcnt vmcnt(0)" ::: "memory"); }
    else         { asm volatile("s_waitcnt vmcnt(6)" ::: "memory"); }  // (t,hi) in
    CBAR();
    domfma(4);
    CBAR();
    // ---- phase 2: kk1, M-frags 0-3 (reads A-hi,B-hi; stages (t+2,A-lo))
    rdA(1, 0); rdB(1);
    stagePart(P0 + 8);
    CBAR();
    domfma(0);
    CBAR();
    // ---- phase 3: kk1, M-frags 4-7 (stages (t+2,B-lo))
    rdA(1, 1);
    stagePart(P0 + 9);
    if (t == 14)      { asm volatile("s_waitcnt vmcnt(3)" ::: "memory"); }
    else if (t < 14)  { asm volatile("s_waitcnt vmcnt(6)" ::: "memory"); } // (t+1,lo)
    CBAR();
    domfma(4);
    CBAR();
  }

  // ---- fused epilogue: bias + rotary + scale + per-consumer layouts
  // n in [0,3072): qkv = n>>10; head h = (n&1023)>>6; d = n&63
#pragma unroll
  for (int j = 0; j < 3; j++) {
    int n = n0 + wn + j * 16 + lr;
    int qkv = n >> 10, nn = n & 1023;
    float bias = (qkv == 0 ? bias0 : qkv == 1 ? bias1 : bias2)[nn];
    int h = nn >> 6, d = nn & 63;
    if (qkv == 2) {
      // V: no rotary; fragment-order layout, pack 4 consecutive keys per store
#pragma unroll
      for (int i = 0; i < 8; i++) {
        int t0 = m0 + wm + i * 16 + quad * 4;
        int b = t0 >> 11, tt = t0 & 2047;
        size_t bb = (size_t)((b << 4) + h) * (TT * 64);
        int kk0 = tt & 63;
        size_t off = bb + (size_t)(tt >> 6) * 4096 +
                     (size_t)((kk0 >> 3) << 9) + (d << 3) + (kk0 & 7);
        ushort4 pk;
        pk.x = f2bf(acc[i][j][0] + bias);
        pk.y = f2bf(acc[i][j][1] + bias);
        pk.z = f2bf(acc[i][j][2] + bias);
        pk.w = f2bf(acc[i][j][3] + bias);
        *(ushort4*)(Vo + off) = pk;
      }
    } else {
#pragma unroll
      for (int i = 0; i < 8; i++)
#pragma unroll
        for (int r = 0; r < 4; r++) {
          int m = m0 + wm + i * 16 + quad * 4 + r;
          float vb = acc[i][j][r] + bias;
          // rotary pair (d^1) lives in lane^1 (same row, adjacent column)
          float pv = __shfl_xor(vb, 1);
          float val = (n & 1) ? pv : -pv;
          int b = m >> 11, t = m & 2047;
          size_t base = (size_t)((b << 4) + h) * (TT * 64);
          if (qkv == 0) {                       // Q: plain (B,H,T,64), pre-scaled
            Qo[base + (size_t)t * 64 + d] = f2bf(val * 0.125f);
          } else {                              // K: fragment-order per 64-row tile
            int kk = t & 63;
            size_t off = base + (size_t)(t >> 6) * 4096 +
                         (size_t)((d >> 3) << 9) + (kk << 3) + (d & 7);
            Ko[off] = f2bf(val);
          }
        }
    }
  }
}

// ---------------------------------------------------------------- out-proj GEMM (r9)
// C = A * B^T + bias, fp32 out. 64x128 tile, BK=64, 16 barriers.
__global__ __launch_bounds__(256) void gemm_op(
    const unsigned short* __restrict__ A, const unsigned short* __restrict__ Bm,
    const float* __restrict__ bias0, float* __restrict__ Co) {
  const int tid = threadIdx.x;
  const int wave = tid >> 6, lane = tid & 63;
  const int lr = lane & 15, quad = lane >> 4;
  const int m0 = blockIdx.y * 64, n0 = blockIdx.x * 128;
  __shared__ __align__(16) unsigned short sA[2][64 * 64];
  __shared__ __align__(16) unsigned short sB[2][128 * 64];
  const f32x4 zero = {0.f, 0.f, 0.f, 0.f};
  f32x4 acc[2][4];
#pragma unroll
  for (int i = 0; i < 2; i++)
#pragma unroll
    for (int j = 0; j < 4; j++) acc[i][j] = zero;
  const int wm = (wave >> 1) * 32, wn = (wave & 1) * 64;

  auto swz = [](int row) { return ((row & 1) << 2) | ((row >> 1) & 3); };

  auto stage = [&](int kt, int buf) {
    const int k0 = kt * 64;
#pragma unroll
    for (int rep = 0; rep < 2; ++rep) {       // A: 64 rows x 64
      int fb = rep * 2048 + wave * 512;
      int fl = fb + lane * 8;
      int row = fl >> 6, pc = (fl >> 3) & 7;
      async16(A + (size_t)(m0 + row) * 1024 + k0 + ((pc ^ swz(row)) << 3), &sA[buf][fb]);
    }
#pragma unroll
    for (int rep = 0; rep < 4; ++rep) {       // B: 128 rows x 64
      int fb = rep * 2048 + wave * 512;
      int fl = fb + lane * 8;
      int row = fl >> 6, pc = (fl >> 3) & 7;
      async16(Bm + (size_t)(n0 + row) * 1024 + k0 + ((pc ^ swz(row)) << 3), &sB[buf][fb]);
    }
  };

  stage(0, 0);
  for (int kt = 0; kt < 16; ++kt) {
    const int buf = kt & 1;
    __syncthreads();                 // staged tile kt visible; prev compute done
    if (kt + 1 < 16) stage(kt + 1, buf ^ 1);
#pragma unroll
    for (int ks = 0; ks < 2; ++ks) {          // two 32-K windows per staged tile
      bfrag af[2], bfr[4];
#pragma unroll
      for (int i = 0; i < 2; i++) {
        int ra = wm + i * 16 + lr;
        af[i] = *(const bfrag*)&sA[buf][ra * 64 + (((ks * 4 + quad) ^ swz(ra)) << 3)];
      }
#pragma unroll
      for (int j = 0; j < 4; j++) {
        int rb = wn + j * 16 + lr;
        bfr[j] = *(const bfrag*)&sB[buf][rb * 64 + (((ks * 4 + quad) ^ swz(rb)) << 3)];
      }
#pragma unroll
      for (int i = 0; i < 2; i++)
#pragma unroll
        for (int j = 0; j < 4; j++)
          acc[i][j] = __builtin_amdgcn_mfma_f32_16x16x32_bf16(af[i], bfr[j], acc[i][j], 0, 0, 0);
    }
  }

#pragma unroll
  for (int j = 0; j < 4; j++) {
    int n = n0 + wn + j * 16 + lr;
    float bias = bias0[n];
#pragma unroll
    for (int i = 0; i < 2; i++)
#pragma unroll
      for (int r = 0; r < 4; r++) {
        int m = m0 + wm + i * 16 + quad * 4 + r;
        Co[(size_t)m * 1024 + n] = acc[i][j][r] + bias;
      }
  }
}

// ---------------------------------------------------------------- flash attention
// Block = 512 threads (8 waves), Q-tile PAIR (qt=p, 31-p); waves 0-3 = long
// stream, 4-7 = short. Bc=128: each barrier stages TWO 64-key tiles (contiguous
// in the fragment-order layout) and the 64-key body runs twice between barriers
// -> barriers per block drop 17-32 to 9-17, and the vmcnt drain at each barrier
// waits on loads issued a full double compute-phase earlier (fully landed).
// LDS 80 KB -> exactly 2 blocks/CU at 512 thr. S^T = mfma(K,Q) (lane&15=q),
// fixed-max softmax (m=11), per-wave P^T LDS roundtrip, PV = mfma(V^T,P^T).
__global__ __launch_bounds__(512, 4) void flash_kernel(
    const unsigned short* __restrict__ Qg, const unsigned short* __restrict__ Kg,
    const unsigned short* __restrict__ Vg, unsigned short* __restrict__ Og) {
  const int p = blockIdx.x;                 // 0..15
  const int bh = blockIdx.y;
  const int tid = threadIdx.x, wave = tid >> 6, lane = tid & 63;
  const int lr = lane & 15, quad = lane >> 4;
  __shared__ __align__(16) unsigned short sK[2][8192];
  __shared__ __align__(16) unsigned short sV[2][8192];
  __shared__ __align__(16) unsigned short sP[8][1024];   // per-wave P^T buffer
  const size_t base = (size_t)bh * (TT * 64);
  const int st = wave >> 2;                 // 0 = long stream, 1 = short stream
  const int qt = st ? p : (31 - p);
  const int nS = st ? (p + 1) : (32 - p);   // active 64-key tiles for this wave
  const int nB = 32 - p;                    // long-stream tile count
  const int npair = (nB + 1) >> 1;          // 128-key steps
  const int qg = qt * 64 + (wave & 3) * 16 + lr;   // this lane's q row
  const f32x4 zero = {0.f, 0.f, 0.f, 0.f};

  bfrag qf0, qf1;
  {
    const unsigned short* qr = Qg + base + (size_t)qg * 64;
    qf0 = *(const bfrag*)(qr + quad * 8);
    qf1 = *(const bfrag*)(qr + 32 + quad * 8);
  }
  f32x4 o[4];
  float rs = 0.f;
#pragma unroll
  for (int j = 0; j < 4; j++) o[j] = zero;

  const unsigned short* kgb = Kg + base;
  const unsigned short* vgb = Vg + base;

  // stage pair 0 (tiles 0,1) into buf 0: 8 waves x 2 reps x 1KB each for K and V
#pragma unroll
  for (int rep = 0; rep < 2; ++rep) {
    int fb = rep * 4096 + wave * 512;
    async16(kgb + fb + lane * 8, &sK[0][fb]);
    async16(vgb + fb + lane * 8, &sV[0][fb]);
  }

  const int pwr = lr * 8 + (quad & 1) * 4;  // P-write column part
  const int pq2 = quad >> 1;

  for (int ktb = 0; ktb < npair; ++ktb) {
    const int buf = ktb & 1;
    __syncthreads();                        // staged pair ktb ready; prev compute done
    if (ktb + 1 < npair) {                  // prefetch next pair (in-bounds even if
#pragma unroll                              //  last pair is half: tile idx <= 31)
      for (int rep = 0; rep < 2; ++rep) {
        int fb = rep * 4096 + wave * 512;
        const size_t g = (size_t)(ktb + 1) * 8192 + fb + lane * 8;
        async16(kgb + g, &sK[buf ^ 1][fb]);
        async16(vgb + g, &sV[buf ^ 1][fb]);
      }
    }
#pragma unroll
    for (int sub = 0; sub < 2; ++sub) {
      const int kt = ktb * 2 + sub;
      if (kt < nS) {                        // wave-uniform activity guard
        const int hb = sub * 4096;          // 64-key half within the staged pair
        // S^T: lane&15 = q, rows = keys
        f32x4 sT[4];
#pragma unroll
        for (int ct = 0; ct < 4; ct++) {
          int row8 = (ct * 16 + lr) * 8;
          bfrag k0 = *(const bfrag*)&sK[buf][hb + quad * 512 + row8];
          bfrag k1 = *(const bfrag*)&sK[buf][hb + (4 + quad) * 512 + row8];
          f32x4 t = __builtin_amdgcn_mfma_f32_16x16x32_bf16(k0, qf0, zero, 0, 0, 0);
          sT[ct]  = __builtin_amdgcn_mfma_f32_16x16x32_bf16(k1, qf1, t,    0, 0, 0);
        }
        const bool diag = (kt == nS - 1);
#pragma unroll
        for (int ct = 0; ct < 4; ++ct) {
          float e[4];
#pragma unroll
          for (int r = 0; r < 4; ++r)
            e[r] = __expf(sT[ct][r] - 11.0f);   // fixed max m=11
          if (diag) {
#pragma unroll
            for (int r = 0; r < 4; ++r) {
              int key = kt * 64 + ct * 16 + quad * 4 + r;
              if (key > qg) e[r] = 0.f;
            }
          }
          rs += (e[0] + e[1]) + (e[2] + e[3]);
          uint2 w;
          w.x = pack2bf(e[0], e[1]);
          w.y = pack2bf(e[2], e[3]);
          *(uint2*)&sP[wave][(ct * 2 + pq2) * 128 + pwr] = w;   // P^T chunk-major
        }
        bfrag pf0 = *(const bfrag*)&sP[wave][quad * 128 + lr * 8];        // keys 0-31
        bfrag pf1 = *(const bfrag*)&sP[wave][(4 + quad) * 128 + lr * 8];  // keys 32-63
#pragma unroll
        for (int j = 0; j < 4; j++) {
          int row8 = (j * 16 + lr) * 8;
          bfrag v0 = *(const bfrag*)&sV[buf][hb + quad * 512 + row8];     // A-frag m=d
          bfrag v1 = *(const bfrag*)&sV[buf][hb + (4 + quad) * 512 + row8];
          o[j] = __builtin_amdgcn_mfma_f32_16x16x32_bf16(v0, pf0, o[j], 0, 0, 0);
          o[j] = __builtin_amdgcn_mfma_f32_16x16x32_bf16(v1, pf1, o[j], 0, 0, 0);
        }
      }
    }
  }

  // final l reduce across quads (lanes lr, lr+16, lr+32, lr+48 share q)
  rs += __shfl_xor(rs, 16); rs += __shfl_xor(rs, 32);
  const float inv = 1.0f / rs;

  // epilogue: O^T (lane=q, regs=d) -> (B,T,D) bf16, 8B packed stores
  const int b = bh >> 4, h = bh & 15;
#pragma unroll
  for (int j = 0; j < 4; j++) {
    ushort4 pk;
    pk.x = f2bf_hw(o[j][0] * inv); pk.y = f2bf_hw(o[j][1] * inv);
    pk.z = f2bf_hw(o[j][2] * inv); pk.w = f2bf_hw(o[j][3] * inv);
    int col = h * 64 + j * 16 + quad * 4;
    *(ushort4*)(Og + (size_t)(b * TT + qg) * 1024 + col) = pk;
  }
}

// ---------------------------------------------------------------- launch
extern "C" void kernel_launch(void* const* d_in, const int* in_sizes, int n_in,
                              void* d_out, int out_size, void* d_ws, size_t ws_size,
                              hipStream_t stream) {
  const float* x  = (const float*)d_in[0];
  const float* Wq = (const float*)d_in[1];
  const float* bq = (const float*)d_in[2];
  const float* Wk = (const float*)d_in[3];
  const float* bk = (const float*)d_in[4];
  const float* Wv = (const float*)d_in[5];
  const float* bv = (const float*)d_in[6];
  const float* Wo = (const float*)d_in[7];
  const float* bo = (const float*)d_in[8];
  float* out = (float*)d_out;

  unsigned short* ws = (unsigned short*)d_ws;
  unsigned short* xb   = ws;                                // 4M elems
  unsigned short* wqkv = ws + (size_t)4 * 1024 * 1024;      // 3M
  unsigned short* wob  = ws + (size_t)7 * 1024 * 1024;      // 1M
  unsigned short* Qb   = ws + (size_t)8 * 1024 * 1024;      // 4M
  unsigned short* Kb   = ws + (size_t)12 * 1024 * 1024;     // 4M
  unsigned short* Vb   = ws + (size_t)16 * 1024 * 1024;     // 4M
  unsigned short* Ob   = ws + (size_t)20 * 1024 * 1024;     // 4M -> 48MB total

  cvt_kernel<<<dim3(8192), dim3(256), 0, stream>>>(x, Wq, Wk, Wv, Wo, xb, wqkv, wob);
  gemm_qkv<<<dim3(256), dim3(512), 0, stream>>>(xb, wqkv, bq, bk, bv, Qb, Kb, Vb);
  flash_kernel<<<dim3(16, 32), dim3(512), 0, stream>>>(Qb, Kb, Vb, Ob);
  gemm_op<<<dim3(8, 64), dim3(256), 0, stream>>>(Ob, wob, bo, out);
}

// Round 4
// 182.772 us; speedup vs baseline: 1.0192x; 1.0192x over previous
//
#include <hip/hip_runtime.h>
#include <stdint.h>

#define DM 1024
#define NH 16
#define HD 64
#define BB 2
#define TT 2048
#define MT (BB*TT)   // 4096 rows total

typedef __bf16 bfrag __attribute__((ext_vector_type(8)));     // 8 bf16 = 4 VGPR (MFMA A/B)
typedef float  f32x4 __attribute__((ext_vector_type(4)));     // MFMA C/D

__device__ __forceinline__ unsigned short f2bf(float f) {
  union { float f; unsigned u; } v; v.f = f;
  unsigned r = v.u + 0x7fffu + ((v.u >> 16) & 1u);  // RNE
  return (unsigned short)(r >> 16);
}

__device__ __forceinline__ unsigned short f2bf_hw(float f) {
  __bf16 b = (__bf16)f;                 // hardware cvt
  union { __bf16 b; unsigned short u; } v; v.b = b;
  return v.u;
}

__device__ __forceinline__ unsigned int pack2bf(float a, float b) {
  union { __bf16 h[2]; unsigned int u; } v;
  v.h[0] = (__bf16)a; v.h[1] = (__bf16)b;   // fuses to v_cvt_pk_bf16_f32
  return v.u;
}

__device__ __forceinline__ void async16(const void* g, void* l) {
  __builtin_amdgcn_global_load_lds(
      (const __attribute__((address_space(1))) unsigned int*)g,
      (__attribute__((address_space(3))) unsigned int*)l, 16, 0, 0);
}

// compiler-fenced raw barrier: keeps hipcc from migrating LDS/VMEM ops across
// the hardware barrier while NOT draining vmcnt (unlike __syncthreads()).
#define CBAR() do { asm volatile("" ::: "memory"); \
                    __builtin_amdgcn_s_barrier();  \
                    asm volatile("" ::: "memory"); } while (0)

// ---------------------------------------------------------------- cvt fp32->bf16
__global__ __launch_bounds__(256) void cvt_kernel(
    const float* __restrict__ x,  const float* __restrict__ Wq,
    const float* __restrict__ Wk, const float* __restrict__ Wv,
    const float* __restrict__ Wo,
    unsigned short* __restrict__ xb, unsigned short* __restrict__ wqkv,
    unsigned short* __restrict__ wob) {
  int i = blockIdx.x * 256 + threadIdx.x;       // one float4 group each
  const int NX = MT * DM / 4;                   // 1048576 groups of x
  const int NW = DM * DM / 4;                   // 262144 per weight
  const float* src; unsigned short* dst; int off;
  if      (i < NX)        { src = x;  dst = xb;              off = i; }
  else if (i < NX + NW)   { src = Wq; dst = wqkv;            off = i - NX; }
  else if (i < NX + 2*NW) { src = Wk; dst = wqkv + DM*DM;    off = i - NX - NW; }
  else if (i < NX + 3*NW) { src = Wv; dst = wqkv + 2*DM*DM;  off = i - NX - 2*NW; }
  else                    { src = Wo; dst = wob;             off = i - NX - 3*NW; }
  float4 v = ((const float4*)src)[off];
  ushort4 o;
  o.x = f2bf(v.x); o.y = f2bf(v.y); o.z = f2bf(v.z); o.w = f2bf(v.w);
  ((ushort4*)dst)[off] = o;
}

// ---------------------------------------------------------------- QKV GEMM
// 256x192 tile, BK=64, 8 waves (4M x 2N), 4 phases per K-tile, counted vmcnt,
// SINGLE barrier per phase. Grid = 256 blocks = 1/CU, 100% fill.
//
// Round-4 change vs round-3 (which tied rounds 0-2 at ~46 us, MfmaUtil 20%,
// both pipes ~80% idle): the post-MFMA barrier forced all 8 waves to finish
// MFMAs before any wave issued the next phase's LDS reads (lockstep). Phase
// is now [ds_reads, stage-issue, (vmcnt wait), BARRIER, MFMA]: one barrier.
// Ordering proof: reads(P) pre-BAR(P), conflicting re-stage is post-BAR(P)
// (slot ring distance 8 parts = 2 phases, conflict pair is reads(P) vs
// stage(P+1)); staged-data visibility: every vmcnt wait is pre-barrier and
// consuming reads are post-that-barrier; MFMA hazards are register-only.
// Waves now overlap: A's MFMA runs while B reads/stages. Also 4Mx2N wave
// grid (was 2Mx4N): LDS read amplification 176->160 KB per K-tile.
//
// LDS ring: 8 slots = {A,B} x {K-lo,K-hi} x {2 bufs}. Part h = 4*t + pi,
// pi: 0=A-lo 1=B-lo 2=A-hi 3=B-hi. Phase P (=4t+p) stages part h=P+6.
// Reads: ph0 {A-lo, B-lo[0:3)}, ph1 {B-lo[3:6), af reused}, ph2 {A-hi,
// B-hi[0:3)}, ph3 {B-hi[3:6)}. Per-wave loads/tile: g0(waves 0-3)=8,
// g1(waves 4-7)=6; uniform STRICTER g1 residuals: 6 steady (ph1: parts
// <=4t+3 landed for ph2; ph3: <=4t+5 for next ph0), 3 at t=14/ph3, 0 at
// t=15/ph1. Swizzle: 32-elem rows, 16B chunk c ^= (row>>1)&3 in gaddr.
__global__ __launch_bounds__(512, 2) void gemm_qkv(
    const unsigned short* __restrict__ A, const unsigned short* __restrict__ Bm,
    const float* __restrict__ bias0, const float* __restrict__ bias1,
    const float* __restrict__ bias2,
    unsigned short* __restrict__ Qo, unsigned short* __restrict__ Ko,
    unsigned short* __restrict__ Vo) {
  const int tid = threadIdx.x;
  const int wave = tid >> 6, lane = tid & 63;
  const int lr = lane & 15, quad = lane >> 4;
  // XCD swizzle: 256 WGs = 8 XCDs x 32; n-panel-major within an XCD chunk
  const int flat = blockIdx.x;
  const int s = (flat & 7) * 32 + (flat >> 3);
  const int m0 = (s & 15) * 256, n0 = (s >> 4) * 192;

  __shared__ __align__(16) unsigned short sA[2][2][256 * 32];  // 64 KB
  __shared__ __align__(16) unsigned short sB[2][2][192 * 32];  // 48 KB

  const f32x4 zero = {0.f, 0.f, 0.f, 0.f};
  f32x4 acc[4][6];
#pragma unroll
  for (int i = 0; i < 4; i++)
#pragma unroll
    for (int j = 0; j < 6; j++) acc[i][j] = zero;

  const int wm = (wave >> 1) * 64, wn = (wave & 1) * 96;

  auto stagePart = [&](int h) {
    if (h >= 64) return;                  // 16 tiles x 4 parts
    const int ts = h >> 2, pi = h & 3;
    const int buf = ts & 1, hk = pi >> 1; // hk: 0=lo,1=hi
    const int k0 = ts * 64 + (hk << 5);
    if (pi & 1) {                         // B part: 192 rows x 32 = 12 chunks
      unsigned short* dst = &sB[buf][hk][0];
      {
        int fb = wave * 512;
        int fl = fb + lane * 8;
        int row = fl >> 5, c = (fl >> 3) & 3;
        async16(Bm + (size_t)(n0 + row) * 1024 + k0 + ((c ^ ((row >> 1) & 3)) << 3),
                dst + fb);
      }
      if (wave < 4) {
        int fb = 4096 + wave * 512;
        int fl = fb + lane * 8;
        int row = fl >> 5, c = (fl >> 3) & 3;
        async16(Bm + (size_t)(n0 + row) * 1024 + k0 + ((c ^ ((row >> 1) & 3)) << 3),
                dst + fb);
      }
    } else {                              // A part: 256 rows x 32, 2 calls/wave
      unsigned short* dst = &sA[buf][hk][0];
#pragma unroll
      for (int rep = 0; rep < 2; ++rep) {
        int fb = rep * 4096 + wave * 512;
        int fl = fb + lane * 8;
        int row = fl >> 5, c = (fl >> 3) & 3;
        async16(A + (size_t)(m0 + row) * 1024 + k0 + ((c ^ ((row >> 1) & 3)) << 3),
                dst + fb);
      }
    }
  };

  // prologue: parts 0..5 = tile0 complete + tile1 lo; wait tile0-lo landed
#pragma unroll
  for (int h = 0; h < 6; ++h) stagePart(h);
  asm volatile("s_waitcnt vmcnt(6)" ::: "memory");
  CBAR();

  bfrag af[4], bf[3];
#pragma unroll 1
  for (int t = 0; t < 16; ++t) {
    const int buf = t & 1;
    const int P0 = 4 * t;

    auto rdA = [&](int hk) {
#pragma unroll
      for (int i = 0; i < 4; i++) {
        int ra = wm + i * 16 + lr;
        af[i] = *(const bfrag*)&sA[buf][hk][ra * 32 + ((quad ^ ((ra >> 1) & 3)) << 3)];
      }
    };
    auto rdB = [&](int hk, int jh) {
#pragma unroll
      for (int jj = 0; jj < 3; jj++) {
        int rb = wn + (jh * 3 + jj) * 16 + lr;
        bf[jj] = *(const bfrag*)&sB[buf][hk][rb * 32 + ((quad ^ ((rb >> 1) & 3)) << 3)];
      }
    };
    auto domfma = [&](int jh) {
      __builtin_amdgcn_s_setprio(1);
#pragma unroll
      for (int i = 0; i < 4; i++)
#pragma unroll
        for (int jj = 0; jj < 3; jj++)
          acc[i][jh * 3 + jj] = __builtin_amdgcn_mfma_f32_16x16x32_bf16(
              af[i], bf[jj], acc[i][jh * 3 + jj], 0, 0, 0);
      __builtin_amdgcn_s_setprio(0);
    };

    // ---- phase 0: reads A-lo + B-lo[0:3); stages (t+1,A-hi)
    rdA(0); rdB(0, 0);
    stagePart(P0 + 6);
    CBAR();
    domfma(0);
    // ---- phase 1: reads B-lo[3:6) (af reused); stages (t+1,B-hi)
    rdB(0, 1);
    stagePart(P0 + 7);
    if (t == 15) { asm volatile("s_waitcnt vmcnt(0)" ::: "memory"); }
    else         { asm volatile("s_waitcnt vmcnt(6)" ::: "memory"); }  // (t,hi) in
    CBAR();
    domfma(1);
    // ---- phase 2: reads A-hi + B-hi[0:3); stages (t+2,A-lo)
    rdA(1); rdB(1, 0);
    stagePart(P0 + 8);
    CBAR();
    domfma(0);
    // ---- phase 3: reads B-hi[3:6); stages (t+2,B-lo)
    rdB(1, 1);
    stagePart(P0 + 9);
    if (t == 14)      { asm volatile("s_waitcnt vmcnt(3)" ::: "memory"); }
    else if (t < 14)  { asm volatile("s_waitcnt vmcnt(6)" ::: "memory"); } // (t+1,lo)
    CBAR();
    domfma(1);
  }

  // ---- fused epilogue: bias + rotary + scale + per-consumer layouts
  // n in [0,3072): qkv = n>>10; head h = (n&1023)>>6; d = n&63
#pragma unroll
  for (int j = 0; j < 6; j++) {
    int n = n0 + wn + j * 16 + lr;
    int qkv = n >> 10, nn = n & 1023;
    float bias = (qkv == 0 ? bias0 : qkv == 1 ? bias1 : bias2)[nn];
    int h = nn >> 6, d = nn & 63;
    if (qkv == 2) {
      // V: no rotary; fragment-order layout, pack 4 consecutive keys per store
#pragma unroll
      for (int i = 0; i < 4; i++) {
        int t0 = m0 + wm + i * 16 + quad * 4;
        int b = t0 >> 11, tt = t0 & 2047;
        size_t bb = (size_t)((b << 4) + h) * (TT * 64);
        int kk0 = tt & 63;
        size_t off = bb + (size_t)(tt >> 6) * 4096 +
                     (size_t)((kk0 >> 3) << 9) + (d << 3) + (kk0 & 7);
        ushort4 pk;
        pk.x = f2bf(acc[i][j][0] + bias);
        pk.y = f2bf(acc[i][j][1] + bias);
        pk.z = f2bf(acc[i][j][2] + bias);
        pk.w = f2bf(acc[i][j][3] + bias);
        *(ushort4*)(Vo + off) = pk;
      }
    } else {
#pragma unroll
      for (int i = 0; i < 4; i++)
#pragma unroll
        for (int r = 0; r < 4; r++) {
          int m = m0 + wm + i * 16 + quad * 4 + r;
          float vb = acc[i][j][r] + bias;
          // rotary pair (d^1) lives in lane^1 (same row, adjacent column)
          float pv = __shfl_xor(vb, 1);
          float val = (n & 1) ? pv : -pv;
          int b = m >> 11, t = m & 2047;
          size_t base = (size_t)((b << 4) + h) * (TT * 64);
          if (qkv == 0) {                       // Q: plain (B,H,T,64), pre-scaled
            Qo[base + (size_t)t * 64 + d] = f2bf(val * 0.125f);
          } else {                              // K: fragment-order per 64-row tile
            int kk = t & 63;
            size_t off = base + (size_t)(t >> 6) * 4096 +
                         (size_t)((d >> 3) << 9) + (kk << 3) + (d & 7);
            Ko[off] = f2bf(val);
          }
        }
    }
  }
}

// ---------------------------------------------------------------- out-proj GEMM (r9)
// C = A * B^T + bias, fp32 out. 64x128 tile, BK=64, 16 barriers.
__global__ __launch_bounds__(256) void gemm_op(
    const unsigned short* __restrict__ A, const unsigned short* __restrict__ Bm,
    const float* __restrict__ bias0, float* __restrict__ Co) {
  const int tid = threadIdx.x;
  const int wave = tid >> 6, lane = tid & 63;
  const int lr = lane & 15, quad = lane >> 4;
  const int m0 = blockIdx.y * 64, n0 = blockIdx.x * 128;
  __shared__ __align__(16) unsigned short sA[2][64 * 64];
  __shared__ __align__(16) unsigned short sB[2][128 * 64];
  const f32x4 zero = {0.f, 0.f, 0.f, 0.f};
  f32x4 acc[2][4];
#pragma unroll
  for (int i = 0; i < 2; i++)
#pragma unroll
    for (int j = 0; j < 4; j++) acc[i][j] = zero;
  const int wm = (wave >> 1) * 32, wn = (wave & 1) * 64;

  auto swz = [](int row) { return ((row & 1) << 2) | ((row >> 1) & 3); };

  auto stage = [&](int kt, int buf) {
    const int k0 = kt * 64;
#pragma unroll
    for (int rep = 0; rep < 2; ++rep) {       // A: 64 rows x 64
      int fb = rep * 2048 + wave * 512;
      int fl = fb + lane * 8;
      int row = fl >> 6, pc = (fl >> 3) & 7;
      async16(A + (size_t)(m0 + row) * 1024 + k0 + ((pc ^ swz(row)) << 3), &sA[buf][fb]);
    }
#pragma unroll
    for (int rep = 0; rep < 4; ++rep) {       // B: 128 rows x 64
      int fb = rep * 2048 + wave * 512;
      int fl = fb + lane * 8;
      int row = fl >> 6, pc = (fl >> 3) & 7;
      async16(Bm + (size_t)(n0 + row) * 1024 + k0 + ((pc ^ swz(row)) << 3), &sB[buf][fb]);
    }
  };

  stage(0, 0);
  for (int kt = 0; kt < 16; ++kt) {
    const int buf = kt & 1;
    __syncthreads();                 // staged tile kt visible; prev compute done
    if (kt + 1 < 16) stage(kt + 1, buf ^ 1);
#pragma unroll
    for (int ks = 0; ks < 2; ++ks) {          // two 32-K windows per staged tile
      bfrag af[2], bfr[4];
#pragma unroll
      for (int i = 0; i < 2; i++) {
        int ra = wm + i * 16 + lr;
        af[i] = *(const bfrag*)&sA[buf][ra * 64 + (((ks * 4 + quad) ^ swz(ra)) << 3)];
      }
#pragma unroll
      for (int j = 0; j < 4; j++) {
        int rb = wn + j * 16 + lr;
        bfr[j] = *(const bfrag*)&sB[buf][rb * 64 + (((ks * 4 + quad) ^ swz(rb)) << 3)];
      }
#pragma unroll
      for (int i = 0; i < 2; i++)
#pragma unroll
        for (int j = 0; j < 4; j++)
          acc[i][j] = __builtin_amdgcn_mfma_f32_16x16x32_bf16(af[i], bfr[j], acc[i][j], 0, 0, 0);
    }
  }

#pragma unroll
  for (int j = 0; j < 4; j++) {
    int n = n0 + wn + j * 16 + lr;
    float bias = bias0[n];
#pragma unroll
    for (int i = 0; i < 2; i++)
#pragma unroll
      for (int r = 0; r < 4; r++) {
        int m = m0 + wm + i * 16 + quad * 4 + r;
        Co[(size_t)m * 1024 + n] = acc[i][j][r] + bias;
      }
  }
}

// ---------------------------------------------------------------- flash attention
// Block = 512 threads (8 waves), Q-tile PAIR (qt=p, 31-p); waves 0-3 = long
// stream, 4-7 = short. Bc=128: each barrier stages TWO 64-key tiles (contiguous
// in the fragment-order layout) and the 64-key body runs twice between barriers
// -> barriers per block drop 17-32 to 9-17, and the vmcnt drain at each barrier
// waits on loads issued a full double compute-phase earlier (fully landed).
// LDS 80 KB -> exactly 2 blocks/CU at 512 thr. S^T = mfma(K,Q) (lane&15=q),
// fixed-max softmax (m=11), per-wave P^T LDS roundtrip, PV = mfma(V^T,P^T).
__global__ __launch_bounds__(512, 4) void flash_kernel(
    const unsigned short* __restrict__ Qg, const unsigned short* __restrict__ Kg,
    const unsigned short* __restrict__ Vg, unsigned short* __restrict__ Og) {
  const int p = blockIdx.x;                 // 0..15
  const int bh = blockIdx.y;
  const int tid = threadIdx.x, wave = tid >> 6, lane = tid & 63;
  const int lr = lane & 15, quad = lane >> 4;
  __shared__ __align__(16) unsigned short sK[2][8192];
  __shared__ __align__(16) unsigned short sV[2][8192];
  __shared__ __align__(16) unsigned short sP[8][1024];   // per-wave P^T buffer
  const size_t base = (size_t)bh * (TT * 64);
  const int st = wave >> 2;                 // 0 = long stream, 1 = short stream
  const int qt = st ? p : (31 - p);
  const int nS = st ? (p + 1) : (32 - p);   // active 64-key tiles for this wave
  const int nB = 32 - p;                    // long-stream tile count
  const int npair = (nB + 1) >> 1;          // 128-key steps
  const int qg = qt * 64 + (wave & 3) * 16 + lr;   // this lane's q row
  const f32x4 zero = {0.f, 0.f, 0.f, 0.f};

  bfrag qf0, qf1;
  {
    const unsigned short* qr = Qg + base + (size_t)qg * 64;
    qf0 = *(const bfrag*)(qr + quad * 8);
    qf1 = *(const bfrag*)(qr + 32 + quad * 8);
  }
  f32x4 o[4];
  float rs = 0.f;
#pragma unroll
  for (int j = 0; j < 4; j++) o[j] = zero;

  const unsigned short* kgb = Kg + base;
  const unsigned short* vgb = Vg + base;

  // stage pair 0 (tiles 0,1) into buf 0: 8 waves x 2 reps x 1KB each for K and V
#pragma unroll
  for (int rep = 0; rep < 2; ++rep) {
    int fb = rep * 4096 + wave * 512;
    async16(kgb + fb + lane * 8, &sK[0][fb]);
    async16(vgb + fb + lane * 8, &sV[0][fb]);
  }

  const int pwr = lr * 8 + (quad & 1) * 4;  // P-write column part
  const int pq2 = quad >> 1;

  for (int ktb = 0; ktb < npair; ++ktb) {
    const int buf = ktb & 1;
    __syncthreads();                        // staged pair ktb ready; prev compute done
    if (ktb + 1 < npair) {                  // prefetch next pair (in-bounds even if
#pragma unroll                              //  last pair is half: tile idx <= 31)
      for (int rep = 0; rep < 2; ++rep) {
        int fb = rep * 4096 + wave * 512;
        const size_t g = (size_t)(ktb + 1) * 8192 + fb + lane * 8;
        async16(kgb + g, &sK[buf ^ 1][fb]);
        async16(vgb + g, &sV[buf ^ 1][fb]);
      }
    }
#pragma unroll
    for (int sub = 0; sub < 2; ++sub) {
      const int kt = ktb * 2 + sub;
      if (kt < nS) {                        // wave-uniform activity guard
        const int hb = sub * 4096;          // 64-key half within the staged pair
        // S^T: lane&15 = q, rows = keys
        f32x4 sT[4];
#pragma unroll
        for (int ct = 0; ct < 4; ct++) {
          int row8 = (ct * 16 + lr) * 8;
          bfrag k0 = *(const bfrag*)&sK[buf][hb + quad * 512 + row8];
          bfrag k1 = *(const bfrag*)&sK[buf][hb + (4 + quad) * 512 + row8];
          f32x4 t = __builtin_amdgcn_mfma_f32_16x16x32_bf16(k0, qf0, zero, 0, 0, 0);
          sT[ct]  = __builtin_amdgcn_mfma_f32_16x16x32_bf16(k1, qf1, t,    0, 0, 0);
        }
        const bool diag = (kt == nS - 1);
#pragma unroll
        for (int ct = 0; ct < 4; ++ct) {
          float e[4];
#pragma unroll
          for (int r = 0; r < 4; ++r)
            e[r] = __expf(sT[ct][r] - 11.0f);   // fixed max m=11
          if (diag) {
#pragma unroll
            for (int r = 0; r < 4; ++r) {
              int key = kt * 64 + ct * 16 + quad * 4 + r;
              if (key > qg) e[r] = 0.f;
            }
          }
          rs += (e[0] + e[1]) + (e[2] + e[3]);
          uint2 w;
          w.x = pack2bf(e[0], e[1]);
          w.y = pack2bf(e[2], e[3]);
          *(uint2*)&sP[wave][(ct * 2 + pq2) * 128 + pwr] = w;   // P^T chunk-major
        }
        bfrag pf0 = *(const bfrag*)&sP[wave][quad * 128 + lr * 8];        // keys 0-31
        bfrag pf1 = *(const bfrag*)&sP[wave][(4 + quad) * 128 + lr * 8];  // keys 32-63
#pragma unroll
        for (int j = 0; j < 4; j++) {
          int row8 = (j * 16 + lr) * 8;
          bfrag v0 = *(const bfrag*)&sV[buf][hb + quad * 512 + row8];     // A-frag m=d
          bfrag v1 = *(const bfrag*)&sV[buf][hb + (4 + quad) * 512 + row8];
          o[j] = __builtin_amdgcn_mfma_f32_16x16x32_bf16(v0, pf0, o[j], 0, 0, 0);
          o[j] = __builtin_amdgcn_mfma_f32_16x16x32_bf16(v1, pf1, o[j], 0, 0, 0);
        }
      }
    }
  }

  // final l reduce across quads (lanes lr, lr+16, lr+32, lr+48 share q)
  rs += __shfl_xor(rs, 16); rs += __shfl_xor(rs, 32);
  const float inv = 1.0f / rs;

  // epilogue: O^T (lane=q, regs=d) -> (B,T,D) bf16, 8B packed stores
  const int b = bh >> 4, h = bh & 15;
#pragma unroll
  for (int j = 0; j < 4; j++) {
    ushort4 pk;
    pk.x = f2bf_hw(o[j][0] * inv); pk.y = f2bf_hw(o[j][1] * inv);
    pk.z = f2bf_hw(o[j][2] * inv); pk.w = f2bf_hw(o[j][3] * inv);
    int col = h * 64 + j * 16 + quad * 4;
    *(ushort4*)(Og + (size_t)(b * TT + qg) * 1024 + col) = pk;
  }
}

// ---------------------------------------------------------------- launch
extern "C" void kernel_launch(void* const* d_in, const int* in_sizes, int n_in,
                              void* d_out, int out_size, void* d_ws, size_t ws_size,
                              hipStream_t stream) {
  const float* x  = (const float*)d_in[0];
  const float* Wq = (const float*)d_in[1];
  const float* bq = (const float*)d_in[2];
  const float* Wk = (const float*)d_in[3];
  const float* bk = (const float*)d_in[4];
  const float* Wv = (const float*)d_in[5];
  const float* bv = (const float*)d_in[6];
  const float* Wo = (const float*)d_in[7];
  const float* bo = (const float*)d_in[8];
  float* out = (float*)d_out;

  unsigned short* ws = (unsigned short*)d_ws;
  unsigned short* xb   = ws;                                // 4M elems
  unsigned short* wqkv = ws + (size_t)4 * 1024 * 1024;      // 3M
  unsigned short* wob  = ws + (size_t)7 * 1024 * 1024;      // 1M
  unsigned short* Qb   = ws + (size_t)8 * 1024 * 1024;      // 4M
  unsigned short* Kb   = ws + (size_t)12 * 1024 * 1024;     // 4M
  unsigned short* Vb   = ws + (size_t)16 * 1024 * 1024;     // 4M
  unsigned short* Ob   = ws + (size_t)20 * 1024 * 1024;     // 4M -> 48MB total

  cvt_kernel<<<dim3(8192), dim3(256), 0, stream>>>(x, Wq, Wk, Wv, Wo, xb, wqkv, wob);
  gemm_qkv<<<dim3(256), dim3(512), 0, stream>>>(xb, wqkv, bq, bk, bv, Qb, Kb, Vb);
  flash_kernel<<<dim3(16, 32), dim3(512), 0, stream>>>(Qb, Kb, Vb, Ob);
  gemm_op<<<dim3(8, 64), dim3(256), 0, stream>>>(Ob, wob, bo, out);
}